// Round 1
// baseline (566.005 us; speedup 1.0000x reference)
//
#include <hip/hip_runtime.h>
#include <math.h>

#define F 128
#define ZD 272
#define EDIM 16
#define EPS 1e-5f

// ---------------------------------------------------------------------------
// Kernel A: node tables.  tab[n][t][f], t: 0=dst-filter(+bf), 1=dst-softplus(+bs),
// 2=src-filter, 3=src-softplus.  C[n][tf] = sum_k x[n][k] * B[k][tf]
// GEMM M=N, N=512, K=128. Tile 64x64, 4x4 micro-tile, K chunked by 64.
// LDS padded to 76 floats/row: transpose staging writes land 2-way (free).
// ---------------------------------------------------------------------------
__global__ __launch_bounds__(256) void node_gemm(
    const float* __restrict__ x, const float* __restrict__ Wf,
    const float* __restrict__ Ws, const float* __restrict__ bf,
    const float* __restrict__ bs, float* __restrict__ tab, int N)
{
  __shared__ float As[64][76];  // [k][m]
  __shared__ float Bs[64][76];  // [k][n]
  const int bm = blockIdx.x, bn = blockIdx.y;
  const int t = bn >> 1;                 // 0..3
  const int fbase = (bn & 1) * 64;       // 0 or 64
  const float* W = (t & 1) ? Ws : Wf;
  const int koff = (t >= 2) ? F : 0;
  const int tid = threadIdx.x;
  const int kq = (tid & 15) * 4;         // k-quad within chunk
  const int rr = tid >> 4;               // 0..15

  const int tx = tid & 15, ty = tid >> 4;
  const int m0 = ty * 4, n0 = tx * 4;
  float acc[4][4] = {};

  for (int kk = 0; kk < F; kk += 64) {
    // stage A: x[node][kk+k] -> As[k][m]
    #pragma unroll
    for (int it = 0; it < 4; ++it) {
      int row = it * 16 + rr;
      int node = bm * 64 + row;
      float4 v = make_float4(0.f, 0.f, 0.f, 0.f);
      if (node < N) v = *(const float4*)(x + (size_t)node * F + kk + kq);
      As[kq + 0][row] = v.x; As[kq + 1][row] = v.y;
      As[kq + 2][row] = v.z; As[kq + 3][row] = v.w;
    }
    // stage B: W[(fbase+n)][koff+kk+k] -> Bs[k][n]
    #pragma unroll
    for (int it = 0; it < 4; ++it) {
      int n = it * 16 + rr;
      float4 v = *(const float4*)(W + (size_t)(fbase + n) * ZD + koff + kk + kq);
      Bs[kq + 0][n] = v.x; Bs[kq + 1][n] = v.y;
      Bs[kq + 2][n] = v.z; Bs[kq + 3][n] = v.w;
    }
    __syncthreads();
    #pragma unroll 8
    for (int k = 0; k < 64; ++k) {
      float4 a = *(const float4*)&As[k][m0];
      float4 b = *(const float4*)&Bs[k][n0];
      float av[4] = {a.x, a.y, a.z, a.w};
      float bv[4] = {b.x, b.y, b.z, b.w};
      #pragma unroll
      for (int i = 0; i < 4; ++i)
        #pragma unroll
        for (int j = 0; j < 4; ++j)
          acc[i][j] += av[i] * bv[j];
    }
    __syncthreads();
  }

  #pragma unroll
  for (int i = 0; i < 4; ++i) {
    int node = bm * 64 + m0 + i;
    if (node >= N) continue;
    #pragma unroll
    for (int j = 0; j < 4; ++j) {
      int f = fbase + n0 + j;
      float v = acc[i][j];
      if (t == 0) v += bf[f];
      else if (t == 1) v += bs[f];
      tab[(size_t)node * 512 + t * F + f] = v;
    }
  }
}

// ---------------------------------------------------------------------------
// CSR build
// ---------------------------------------------------------------------------
__global__ void count_deg(const int* __restrict__ dst, int* __restrict__ cnt, int E)
{
  int e = blockIdx.x * blockDim.x + threadIdx.x;
  if (e < E) atomicAdd(&cnt[dst[e]], 1);
}

__global__ __launch_bounds__(1024) void scan_k(
    const int* __restrict__ cnt, int* __restrict__ rowptr,
    int* __restrict__ cursor, int N, int cpt)
{
  __shared__ int lds[1024];
  const int tid = threadIdx.x;
  const int base = tid * cpt;
  int run = 0;
  for (int j = 0; j < cpt; ++j) {
    int idx = base + j;
    run += (idx < N) ? cnt[idx] : 0;
  }
  lds[tid] = run;
  __syncthreads();
  for (int off = 1; off < 1024; off <<= 1) {
    int v = (tid >= off) ? lds[tid - off] : 0;
    __syncthreads();
    lds[tid] += v;
    __syncthreads();
  }
  int v = lds[tid] - run;  // exclusive prefix for this thread's chunk
  for (int j = 0; j < cpt; ++j) {
    int idx = base + j;
    if (idx <= N) {
      rowptr[idx] = v;
      if (idx < N) { cursor[idx] = v; v += cnt[idx]; }
    }
  }
}

__global__ void fill_csr(const int* __restrict__ dst, int* __restrict__ cursor,
                         int* __restrict__ eids, int E)
{
  int e = blockIdx.x * blockDim.x + threadIdx.x;
  if (e < E) {
    int pos = atomicAdd(&cursor[dst[e]], 1);
    eids[pos] = e;
  }
}

// ---------------------------------------------------------------------------
// Aggregation: one wave per dst node, 2 features per lane (f0=lane, f1=lane+64).
// msg = sigmoid(tabDF[dst]+tabSF[src]+ea.Wef) * softplus(tabDS[dst]+tabSS[src]+ea.Wes)
// Edge-attr weight slices live in 64 VGPRs per lane. Register accumulate -> 1 store.
// ---------------------------------------------------------------------------
__device__ __forceinline__ float sigm(float v) { return 1.f / (1.f + __expf(-v)); }
__device__ __forceinline__ float splus(float v) {
  return fmaxf(v, 0.f) + log1pf(__expf(-fabsf(v)));
}

__global__ __launch_bounds__(256) void aggregate(
    const float* __restrict__ tab, const int* __restrict__ srcA,
    const float* __restrict__ ea, const int* __restrict__ eids,
    const int* __restrict__ rowptr, const float* __restrict__ Wf,
    const float* __restrict__ Ws, float* __restrict__ agg, int N)
{
  const int lane = threadIdx.x & 63;
  const int wid  = (blockIdx.x * blockDim.x + threadIdx.x) >> 6;
  const int nwav = (gridDim.x * blockDim.x) >> 6;
  const int f0 = lane, f1 = lane + 64;

  float wf0[16], wf1[16], ws0[16], ws1[16];
  #pragma unroll
  for (int q = 0; q < 4; ++q) {
    float4 v;
    v = ((const float4*)(Wf + (size_t)f0 * ZD + 2 * F))[q];
    wf0[4*q] = v.x; wf0[4*q+1] = v.y; wf0[4*q+2] = v.z; wf0[4*q+3] = v.w;
    v = ((const float4*)(Wf + (size_t)f1 * ZD + 2 * F))[q];
    wf1[4*q] = v.x; wf1[4*q+1] = v.y; wf1[4*q+2] = v.z; wf1[4*q+3] = v.w;
    v = ((const float4*)(Ws + (size_t)f0 * ZD + 2 * F))[q];
    ws0[4*q] = v.x; ws0[4*q+1] = v.y; ws0[4*q+2] = v.z; ws0[4*q+3] = v.w;
    v = ((const float4*)(Ws + (size_t)f1 * ZD + 2 * F))[q];
    ws1[4*q] = v.x; ws1[4*q+1] = v.y; ws1[4*q+2] = v.z; ws1[4*q+3] = v.w;
  }

  for (int node = wid; node < N; node += nwav) {
    const size_t nb = (size_t)node * 512;
    const float pdf0 = tab[nb + f0],       pdf1 = tab[nb + f1];
    const float pds0 = tab[nb + F + f0],   pds1 = tab[nb + F + f1];
    float acc0 = 0.f, acc1 = 0.f;
    const int s = rowptr[node], e = rowptr[node + 1];
    for (int p = s; p < e; ++p) {
      const int eid = eids[p];
      const int src = srcA[eid];
      const size_t sb = (size_t)src * 512;
      const float sf0 = tab[sb + 2*F + f0], sf1 = tab[sb + 2*F + f1];
      const float ss0 = tab[sb + 3*F + f0], ss1 = tab[sb + 3*F + f1];
      float ev[16];
      #pragma unroll
      for (int q = 0; q < 4; ++q) {
        float4 v = ((const float4*)(ea + (size_t)eid * EDIM))[q];
        ev[4*q] = v.x; ev[4*q+1] = v.y; ev[4*q+2] = v.z; ev[4*q+3] = v.w;
      }
      float df0 = 0.f, df1 = 0.f, ds0 = 0.f, ds1 = 0.f;
      #pragma unroll
      for (int k = 0; k < 16; ++k) {
        df0 += wf0[k] * ev[k]; df1 += wf1[k] * ev[k];
        ds0 += ws0[k] * ev[k]; ds1 += ws1[k] * ev[k];
      }
      acc0 += sigm(pdf0 + sf0 + df0) * splus(pds0 + ss0 + ds0);
      acc1 += sigm(pdf1 + sf1 + df1) * splus(pds1 + ss1 + ds1);
    }
    agg[(size_t)node * F + f0] = acc0;
    agg[(size_t)node * F + f1] = acc1;
  }
}

// ---------------------------------------------------------------------------
// BatchNorm column stats: sums[f] = sum_n agg[n][f], sums[128+f] = sum sq
// ---------------------------------------------------------------------------
__global__ __launch_bounds__(256) void bn_stats(
    const float* __restrict__ agg, float* __restrict__ sums, int N)
{
  const int f = threadIdx.x & 127;
  const int h = threadIdx.x >> 7;
  float s = 0.f, ss = 0.f;
  for (int r = blockIdx.x * 2 + h; r < N; r += gridDim.x * 2) {
    float v = agg[(size_t)r * F + f];
    s += v; ss += v * v;
  }
  atomicAdd(&sums[f], s);
  atomicAdd(&sums[F + f], ss);
}

// ---------------------------------------------------------------------------
// Finalize: BN -> +x -> LN -> relu -> +x.  One wave per node; reads+writes agg
// (in d_out) in place.
// ---------------------------------------------------------------------------
__global__ __launch_bounds__(256) void finalize(
    const float* __restrict__ x, float* __restrict__ out,
    const float* __restrict__ sums, const float* __restrict__ bng,
    const float* __restrict__ bnb, const float* __restrict__ lng,
    const float* __restrict__ lnb, int N)
{
  const int lane = threadIdx.x & 63;
  const int wid  = (blockIdx.x * blockDim.x + threadIdx.x) >> 6;
  const int nwav = (gridDim.x * blockDim.x) >> 6;
  const int f0 = lane, f1 = lane + 64;
  const float invN = 1.f / (float)N;

  float mu0 = sums[f0] * invN, vv0 = sums[F + f0] * invN - mu0 * mu0;
  float mu1 = sums[f1] * invN, vv1 = sums[F + f1] * invN - mu1 * mu1;
  float sc0 = rsqrtf(vv0 + EPS) * bng[f0], sh0 = bnb[f0] - mu0 * sc0;
  float sc1 = rsqrtf(vv1 + EPS) * bng[f1], sh1 = bnb[f1] - mu1 * sc1;
  float g0 = lng[f0], g1 = lng[f1], be0 = lnb[f0], be1 = lnb[f1];

  for (int node = wid; node < N; node += nwav) {
    const size_t b = (size_t)node * F;
    float x0 = x[b + f0], x1 = x[b + f1];
    float h0 = out[b + f0] * sc0 + sh0 + x0;
    float h1 = out[b + f1] * sc1 + sh1 + x1;
    float s = h0 + h1, q = h0 * h0 + h1 * h1;
    #pragma unroll
    for (int o = 32; o > 0; o >>= 1) {
      s += __shfl_xor(s, o, 64);
      q += __shfl_xor(q, o, 64);
    }
    float mu = s * (1.f / 128.f);
    float var = q * (1.f / 128.f) - mu * mu;
    float rs = rsqrtf(var + EPS);
    float y0 = fmaxf((h0 - mu) * rs * g0 + be0, 0.f) + x0;
    float y1 = fmaxf((h1 - mu) * rs * g1 + be1, 0.f) + x1;
    out[b + f0] = y0;
    out[b + f1] = y1;
  }
}

// ---------------------------------------------------------------------------
extern "C" void kernel_launch(void* const* d_in, const int* in_sizes, int n_in,
                              void* d_out, int out_size, void* d_ws, size_t ws_size,
                              hipStream_t stream)
{
  const float* x   = (const float*)d_in[0];
  const int*   ei  = (const int*)d_in[1];
  const float* ea  = (const float*)d_in[2];
  const float* Wf  = (const float*)d_in[3];
  const float* bf  = (const float*)d_in[4];
  const float* Ws  = (const float*)d_in[5];
  const float* bs  = (const float*)d_in[6];
  const float* bng = (const float*)d_in[7];
  const float* bnb = (const float*)d_in[8];
  const float* lng = (const float*)d_in[9];
  const float* lnb = (const float*)d_in[10];

  const int N = in_sizes[0] / F;
  const int E = in_sizes[1] / 2;
  const int* src = ei;
  const int* dst = ei + E;
  float* out = (float*)d_out;

  char* w = (char*)d_ws;
  size_t off = 0;
  auto up = [](size_t v) { return (v + 255) & ~(size_t)255; };
  float* tab    = (float*)(w + off); off = up(off + (size_t)N * 512 * sizeof(float));
  int*   eids   = (int*)(w + off);   off = up(off + (size_t)E * sizeof(int));
  int*   rowptr = (int*)(w + off);   off = up(off + (size_t)(N + 1) * sizeof(int));
  int*   cursor = (int*)(w + off);   off = up(off + (size_t)N * sizeof(int));
  int*   cnt    = (int*)(w + off);   off = up(off + (size_t)N * sizeof(int));
  float* sums   = (float*)(w + off); off = up(off + 256 * sizeof(float));

  hipMemsetAsync(cnt, 0, (size_t)N * sizeof(int), stream);
  hipMemsetAsync(sums, 0, 256 * sizeof(float), stream);

  node_gemm<<<dim3((N + 63) / 64, 8), 256, 0, stream>>>(x, Wf, Ws, bf, bs, tab, N);
  count_deg<<<(E + 255) / 256, 256, 0, stream>>>(dst, cnt, E);
  const int cpt = (N + 1 + 1023) / 1024;
  scan_k<<<1, 1024, 0, stream>>>(cnt, rowptr, cursor, N, cpt);
  fill_csr<<<(E + 255) / 256, 256, 0, stream>>>(dst, cursor, eids, E);
  int aggBlocks = (N + 3) / 4; if (aggBlocks > 2560) aggBlocks = 2560;
  aggregate<<<aggBlocks, 256, 0, stream>>>(tab, src, ea, eids, rowptr, Wf, Ws, out, N);
  bn_stats<<<256, 256, 0, stream>>>(out, sums, N);
  finalize<<<(N + 3) / 4, 256, 0, stream>>>(x, out, sums, bng, bnb, lng, lnb, N);
}

// Round 2
// 432.862 us; speedup vs baseline: 1.3076x; 1.3076x over previous
//
#include <hip/hip_runtime.h>
#include <math.h>

#define F 128
#define ZD 272
#define EDIM 16
#define EPS 1e-5f

// ---------------------------------------------------------------------------
// Kernel A: node tables. Layout per node (512 floats):
//   [0:128)   dst-filter (+bf)
//   [128:256) dst-softplus (+bs)
//   [256:512) src interleaved: {srcF[f], srcS[f]} pairs -> float2 gather
// GEMM M=N, N=512, K=128. Tile 64x64, 4x4 micro-tile, K chunked by 64.
// ---------------------------------------------------------------------------
__global__ __launch_bounds__(256) void node_gemm(
    const float* __restrict__ x, const float* __restrict__ Wf,
    const float* __restrict__ Ws, const float* __restrict__ bf,
    const float* __restrict__ bs, float* __restrict__ tab, int N)
{
  __shared__ float As[64][76];  // [k][m]
  __shared__ float Bs[64][76];  // [k][n]
  const int bm = blockIdx.x, bn = blockIdx.y;
  const int t = bn >> 1;                 // 0..3
  const int fbase = (bn & 1) * 64;       // 0 or 64
  const float* W = (t & 1) ? Ws : Wf;
  const int koff = (t >= 2) ? F : 0;
  const int tid = threadIdx.x;
  const int kq = (tid & 15) * 4;         // k-quad within chunk
  const int rr = tid >> 4;               // 0..15

  const int tx = tid & 15, ty = tid >> 4;
  const int m0 = ty * 4, n0 = tx * 4;
  float acc[4][4] = {};

  for (int kk = 0; kk < F; kk += 64) {
    #pragma unroll
    for (int it = 0; it < 4; ++it) {
      int row = it * 16 + rr;
      int node = bm * 64 + row;
      float4 v = make_float4(0.f, 0.f, 0.f, 0.f);
      if (node < N) v = *(const float4*)(x + (size_t)node * F + kk + kq);
      As[kq + 0][row] = v.x; As[kq + 1][row] = v.y;
      As[kq + 2][row] = v.z; As[kq + 3][row] = v.w;
    }
    #pragma unroll
    for (int it = 0; it < 4; ++it) {
      int n = it * 16 + rr;
      float4 v = *(const float4*)(W + (size_t)(fbase + n) * ZD + koff + kk + kq);
      Bs[kq + 0][n] = v.x; Bs[kq + 1][n] = v.y;
      Bs[kq + 2][n] = v.z; Bs[kq + 3][n] = v.w;
    }
    __syncthreads();
    #pragma unroll 8
    for (int k = 0; k < 64; ++k) {
      float4 a = *(const float4*)&As[k][m0];
      float4 b = *(const float4*)&Bs[k][n0];
      float av[4] = {a.x, a.y, a.z, a.w};
      float bv[4] = {b.x, b.y, b.z, b.w};
      #pragma unroll
      for (int i = 0; i < 4; ++i)
        #pragma unroll
        for (int j = 0; j < 4; ++j)
          acc[i][j] += av[i] * bv[j];
    }
    __syncthreads();
  }

  #pragma unroll
  for (int i = 0; i < 4; ++i) {
    int node = bm * 64 + m0 + i;
    if (node >= N) continue;
    const size_t nb = (size_t)node * 512;
    #pragma unroll
    for (int j = 0; j < 4; ++j) {
      int f = fbase + n0 + j;
      float v = acc[i][j];
      if (t == 0)      tab[nb + f] = v + bf[f];
      else if (t == 1) tab[nb + F + f] = v + bs[f];
      else             tab[nb + 2 * F + 2 * f + (t - 2)] = v;
    }
  }
}

// ---------------------------------------------------------------------------
// CSR build
// ---------------------------------------------------------------------------
__global__ void count_deg(const int* __restrict__ dst, int* __restrict__ cnt, int E)
{
  int e = blockIdx.x * blockDim.x + threadIdx.x;
  if (e < E) atomicAdd(&cnt[dst[e]], 1);
}

__global__ __launch_bounds__(1024) void scan_k(
    const int* __restrict__ cnt, int* __restrict__ rowptr,
    int* __restrict__ cursor, int N, int cpt)
{
  __shared__ int lds[1024];
  const int tid = threadIdx.x;
  const int base = tid * cpt;
  int run = 0;
  for (int j = 0; j < cpt; ++j) {
    int idx = base + j;
    run += (idx < N) ? cnt[idx] : 0;
  }
  lds[tid] = run;
  __syncthreads();
  for (int off = 1; off < 1024; off <<= 1) {
    int v = (tid >= off) ? lds[tid - off] : 0;
    __syncthreads();
    lds[tid] += v;
    __syncthreads();
  }
  int v = lds[tid] - run;
  for (int j = 0; j < cpt; ++j) {
    int idx = base + j;
    if (idx <= N) {
      rowptr[idx] = v;
      if (idx < N) { cursor[idx] = v; v += cnt[idx]; }
    }
  }
}

__global__ void fill_csr(const int* __restrict__ dst, const int* __restrict__ srcA,
                         int* __restrict__ cursor, int* __restrict__ eids,
                         int* __restrict__ srcs, int E)
{
  int e = blockIdx.x * blockDim.x + threadIdx.x;
  if (e < E) {
    int pos = atomicAdd(&cursor[dst[e]], 1);
    eids[pos] = e;
    srcs[pos] = srcA[e];
  }
}

// ---------------------------------------------------------------------------
// Aggregation: one wave per (node, feature-half); 1 feature per lane.
// Per lane: 32 weight floats in VGPRs (launch_bounds(256,4) -> <=128 VGPRs,
// no scratch). Two independent 1-deep gathers per edge: ea[eid], tab[src].
// ---------------------------------------------------------------------------
__device__ __forceinline__ float sigm(float v) {
  return __builtin_amdgcn_rcpf(1.f + __expf(-v));
}
__device__ __forceinline__ float splus(float v) {
  return fmaxf(v, 0.f) + __logf(1.f + __expf(-fabsf(v)));
}

__global__ __launch_bounds__(256, 4) void aggregate(
    const float* __restrict__ tab, const float* __restrict__ ea,
    const int* __restrict__ eids, const int* __restrict__ srcs,
    const int* __restrict__ rowptr, const float* __restrict__ Wf,
    const float* __restrict__ Ws, float* __restrict__ agg, int N)
{
  const int lane = threadIdx.x & 63;
  const int unit = (blockIdx.x * blockDim.x + threadIdx.x) >> 6;  // (node, half)
  const int node = unit >> 1;
  if (node >= N) return;
  const int f = ((unit & 1) << 6) | lane;  // 0..127

  float wf[16], ws[16];
  #pragma unroll
  for (int q = 0; q < 4; ++q) {
    float4 a = ((const float4*)(Wf + (size_t)f * ZD + 2 * F))[q];
    wf[4*q] = a.x; wf[4*q+1] = a.y; wf[4*q+2] = a.z; wf[4*q+3] = a.w;
    float4 b = ((const float4*)(Ws + (size_t)f * ZD + 2 * F))[q];
    ws[4*q] = b.x; ws[4*q+1] = b.y; ws[4*q+2] = b.z; ws[4*q+3] = b.w;
  }

  const size_t nb = (size_t)node * 512;
  const float pdf = tab[nb + f];
  const float pds = tab[nb + F + f];
  float acc = 0.f;
  const int s = rowptr[node], e = rowptr[node + 1];
  #pragma unroll 2
  for (int p = s; p < e; ++p) {
    const int eid = eids[p];
    const int src = srcs[p];
    const float2 sv = *(const float2*)(tab + (size_t)src * 512 + 2 * F + 2 * f);
    const float4* e4 = (const float4*)(ea + (size_t)eid * EDIM);
    float af = pdf + sv.x;
    float as = pds + sv.y;
    #pragma unroll
    for (int q = 0; q < 4; ++q) {
      float4 v = e4[q];
      af += wf[4*q]*v.x + wf[4*q+1]*v.y + wf[4*q+2]*v.z + wf[4*q+3]*v.w;
      as += ws[4*q]*v.x + ws[4*q+1]*v.y + ws[4*q+2]*v.z + ws[4*q+3]*v.w;
    }
    acc += sigm(af) * splus(as);
  }
  agg[(size_t)node * F + f] = acc;
}

// ---------------------------------------------------------------------------
// BatchNorm column stats
// ---------------------------------------------------------------------------
__global__ __launch_bounds__(256) void bn_stats(
    const float* __restrict__ agg, float* __restrict__ sums, int N)
{
  const int f = threadIdx.x & 127;
  const int h = threadIdx.x >> 7;
  float s = 0.f, ss = 0.f;
  for (int r = blockIdx.x * 2 + h; r < N; r += gridDim.x * 2) {
    float v = agg[(size_t)r * F + f];
    s += v; ss += v * v;
  }
  atomicAdd(&sums[f], s);
  atomicAdd(&sums[F + f], ss);
}

// ---------------------------------------------------------------------------
// Finalize: BN -> +x -> LN -> relu -> +x
// ---------------------------------------------------------------------------
__global__ __launch_bounds__(256) void finalize(
    const float* __restrict__ x, float* __restrict__ out,
    const float* __restrict__ sums, const float* __restrict__ bng,
    const float* __restrict__ bnb, const float* __restrict__ lng,
    const float* __restrict__ lnb, int N)
{
  const int lane = threadIdx.x & 63;
  const int wid  = (blockIdx.x * blockDim.x + threadIdx.x) >> 6;
  const int nwav = (gridDim.x * blockDim.x) >> 6;
  const int f0 = lane, f1 = lane + 64;
  const float invN = 1.f / (float)N;

  float mu0 = sums[f0] * invN, vv0 = sums[F + f0] * invN - mu0 * mu0;
  float mu1 = sums[f1] * invN, vv1 = sums[F + f1] * invN - mu1 * mu1;
  float sc0 = rsqrtf(vv0 + EPS) * bng[f0], sh0 = bnb[f0] - mu0 * sc0;
  float sc1 = rsqrtf(vv1 + EPS) * bng[f1], sh1 = bnb[f1] - mu1 * sc1;
  float g0 = lng[f0], g1 = lng[f1], be0 = lnb[f0], be1 = lnb[f1];

  for (int node = wid; node < N; node += nwav) {
    const size_t b = (size_t)node * F;
    float x0 = x[b + f0], x1 = x[b + f1];
    float h0 = out[b + f0] * sc0 + sh0 + x0;
    float h1 = out[b + f1] * sc1 + sh1 + x1;
    float s = h0 + h1, q = h0 * h0 + h1 * h1;
    #pragma unroll
    for (int o = 32; o > 0; o >>= 1) {
      s += __shfl_xor(s, o, 64);
      q += __shfl_xor(q, o, 64);
    }
    float mu = s * (1.f / 128.f);
    float var = q * (1.f / 128.f) - mu * mu;
    float rs = rsqrtf(var + EPS);
    float y0 = fmaxf((h0 - mu) * rs * g0 + be0, 0.f) + x0;
    float y1 = fmaxf((h1 - mu) * rs * g1 + be1, 0.f) + x1;
    out[b + f0] = y0;
    out[b + f1] = y1;
  }
}

// ---------------------------------------------------------------------------
extern "C" void kernel_launch(void* const* d_in, const int* in_sizes, int n_in,
                              void* d_out, int out_size, void* d_ws, size_t ws_size,
                              hipStream_t stream)
{
  const float* x   = (const float*)d_in[0];
  const int*   ei  = (const int*)d_in[1];
  const float* ea  = (const float*)d_in[2];
  const float* Wf  = (const float*)d_in[3];
  const float* bf  = (const float*)d_in[4];
  const float* Ws  = (const float*)d_in[5];
  const float* bs  = (const float*)d_in[6];
  const float* bng = (const float*)d_in[7];
  const float* bnb = (const float*)d_in[8];
  const float* lng = (const float*)d_in[9];
  const float* lnb = (const float*)d_in[10];

  const int N = in_sizes[0] / F;
  const int E = in_sizes[1] / 2;
  const int* srcA = ei;
  const int* dstA = ei + E;
  float* out = (float*)d_out;

  char* w = (char*)d_ws;
  size_t off = 0;
  auto up = [](size_t v) { return (v + 255) & ~(size_t)255; };
  float* tab    = (float*)(w + off); off = up(off + (size_t)N * 512 * sizeof(float));
  int*   eids   = (int*)(w + off);   off = up(off + (size_t)E * sizeof(int));
  int*   srcs   = (int*)(w + off);   off = up(off + (size_t)E * sizeof(int));
  int*   rowptr = (int*)(w + off);   off = up(off + (size_t)(N + 1) * sizeof(int));
  int*   cursor = (int*)(w + off);   off = up(off + (size_t)N * sizeof(int));
  int*   cnt    = (int*)(w + off);   off = up(off + (size_t)N * sizeof(int));
  float* sums   = (float*)(w + off); off = up(off + 256 * sizeof(float));

  hipMemsetAsync(cnt, 0, (size_t)N * sizeof(int), stream);
  hipMemsetAsync(sums, 0, 256 * sizeof(float), stream);

  node_gemm<<<dim3((N + 63) / 64, 8), 256, 0, stream>>>(x, Wf, Ws, bf, bs, tab, N);
  count_deg<<<(E + 255) / 256, 256, 0, stream>>>(dstA, cnt, E);
  const int cpt = (N + 1 + 1023) / 1024;
  scan_k<<<1, 1024, 0, stream>>>(cnt, rowptr, cursor, N, cpt);
  fill_csr<<<(E + 255) / 256, 256, 0, stream>>>(dstA, srcA, cursor, eids, srcs, E);
  const int units = 2 * N;  // (node, half)
  aggregate<<<(units + 3) / 4, 256, 0, stream>>>(tab, ea, eids, srcs, rowptr, Wf, Ws, out, N);
  bn_stats<<<256, 256, 0, stream>>>(out, sums, N);
  finalize<<<(N + 3) / 4, 256, 0, stream>>>(x, out, sums, bng, bnb, lng, lnb, N);
}